// Round 11
// baseline (181.737 us; speedup 1.0000x reference)
//
#include <hip/hip_runtime.h>

// mRNN B=128, C=64, H=32, T=256 via MFMA 16x16x32 bf16, split-bf16 (hi+lo).
// R11 = H-SPLIT of R8: each chain's step is computed by TWO cooperating
// waves (wave0 = tile0 rows 8q+0..3/lane, wave1 = tile1 rows 8q+4..7).
// 1024 blocks x 128 threads -> 2048 REAL waves = 2/SIMD (R8 had 1/SIMD with
// every stall exposed; R9 proved duplicated occupancy is worthless).
// Per-step state exchange via LDS with ZERO routing VALU: lane record =
// [Bh0..3 | Bl0..3]; each wave ds_write_b64's its half into the right
// slots, one barrier, both waves ds_read_b128 the assembled fragments.
// Parity double-buffer (par = u&1) -> one barrier/step is race-free
// (write at t+2 fenced from partner's read at t by the t+1 barrier).
//
// Arithmetic bit-identical to R8 (absmax must stay 4096): same MFMA order,
// same vinit/repack. Single runtime-dir body (R6/R7: dual-inlined bodies
// fail validation — do not template on dir).
//
// Precision (R5/R8-verified): W=Whi+Wlo, h=hhi+hlo, hi=truncate (exact
// residual), lo=RNE; D = vinit + Whi@hl + Wlo@hh + Whi@hh.
constexpr int Bn = 128, Cn = 64, Hn = 32, Tn = 256;

typedef __attribute__((ext_vector_type(8))) short short8;
typedef __attribute__((ext_vector_type(4))) float f32x4;
typedef __attribute__((ext_vector_type(4))) unsigned int u32x4;
typedef __attribute__((ext_vector_type(2))) unsigned int u32x2;

// pack top16(y):top16(x) -> one u32 (low half = x's top16)
__device__ __forceinline__ unsigned pk_hi(unsigned y, unsigned x) {
  return __builtin_amdgcn_perm(y, x, 0x07060302u);
}

__device__ __forceinline__ void wsplit(float w, short& hi, short& lo) {
  unsigned u = __float_as_uint(w);
  float r = w - __uint_as_float(u & 0xffff0000u);   // exact residual
  unsigned ru = __float_as_uint(r) + 0x8000u;       // RNE-ish lo
  hi = (short)(u >> 16);
  lo = (short)(ru >> 16);
}

__global__ __launch_bounds__(128)
void mrnn_scan(const float* __restrict__ x, const float* __restrict__ m,
               const float* __restrict__ d,
               const float* __restrict__ Wf, const float* __restrict__ Vf,
               const float* __restrict__ cf,
               const float* __restrict__ Wb, const float* __restrict__ Vb,
               const float* __restrict__ cb,
               const float* __restrict__ U,
               float* __restrict__ pf_out, float* __restrict__ pb_out) {
  const int bid = blockIdx.x;               // 1024 blocks
  const int dir = bid >> 9;                 // 0 fwd, 1 bwd
  const int c   = (bid >> 3) & (Cn - 1);
  const int g   = bid & 7;                  // batch group of 16
  const int tid = threadIdx.x;              // 0..127
  const int wave = tid >> 6;                // 0 = tile0, 1 = tile1
  const int lane = tid & 63;
  const int q = lane >> 4;
  const int n = lane & 15;
  const int b = g * 16 + n;

  // exchange: [parity][lane-record of 12 dwords]: [Bh0..3 | Bl0..3 | pad]
  // stride 48B keeps b128 reads 16B-aligned, <=4-way bank aliasing.
  __shared__ __align__(16) unsigned exs[2][64 * 12];
  __shared__ __align__(16) float pbuf[16][4];

  const float* W  = dir ? Wb : Wf;
  const float* V  = dir ? Vb : Vf;
  const float* cc = dir ? cb : cf;

  // ---- A fragment (one tile per wave): A[m=n][k=8q+j],
  // row perm rho(m)=8*(m>>2)+(m&3) + wave*4
  const int ra = 8 * (n >> 2) + (n & 3) + wave * 4;
  short8 Ah, Al;
#pragma unroll
  for (int j = 0; j < 8; ++j) {
    short hi, lo;
    wsplit(W[(c * Hn + ra) * Hn + 8 * q + j], hi, lo);
    Ah[j] = hi; Al[j] = lo;
  }

  // ---- per-lane D rows: 8q + wave*4 + r
  float vx[4], vy[4], vz[4], bs[4], uu[4];
#pragma unroll
  for (int r = 0; r < 4; ++r) {
    const int row = 8 * q + wave * 4 + r;
    const float* vp = V + (c * Hn + row) * 3;
    vx[r] = vp[0]; vy[r] = vp[1]; vz[r] = vp[2];
    bs[r] = cc[c * Hn + row];
    uu[r] = U[c * 2 * Hn + dir * Hn + row];
  }

  // ---- state (full B fragments, read back from LDS each step)
  u32x4 Bh = {0u, 0u, 0u, 0u};
  u32x4 Bl = {0u, 0u, 0u, 0u};

  const long base = ((long)b * Cn + c) * Tn;
  const float* px = x + base;
  const float* pm = m + base;
  const float* pd = d + base;
  float* pout = (dir ? pb_out : pf_out) + base;

  // input schedule (verified): fwd step t reads idx max(t-1,0);
  // bwd step s reads idx min(T-s, T-1). Carry + aligned-quad prefetch.
  float cx, cm2, cd2;
  f32x4 qx, qm, qd;
  if (!dir) {
    cx = px[0]; cm2 = pm[0]; cd2 = pd[0];
    qx = *(const f32x4*)px; qm = *(const f32x4*)pm; qd = *(const f32x4*)pd;
  } else {
    cx = px[Tn - 1]; cm2 = pm[Tn - 1]; cd2 = pd[Tn - 1];
    qx = *(const f32x4*)(px + Tn - 4);
    qm = *(const f32x4*)(pm + Tn - 4);
    qd = *(const f32x4*)(pd + Tn - 4);
  }

  unsigned* rec0 = &exs[0][lane * 12];
  unsigned* rec1 = &exs[1][lane * 12];

  for (int t0 = 0; t0 < Tn; t0 += 4) {
    int qn_ = dir ? (Tn - 8 - t0) : (t0 + 4);
    if (qn_ < 0) qn_ = 0;
    if (qn_ > Tn - 4) qn_ = Tn - 4;
    const f32x4 nqx = *(const f32x4*)(px + qn_);
    const f32x4 nqm = *(const f32x4*)(pm + qn_);
    const f32x4 nqd = *(const f32x4*)(pd + qn_);

    float inx[4], inm[4], ind[4];
    if (!dir) {
      inx[0] = cx;  inx[1] = qx.x; inx[2] = qx.y; inx[3] = qx.z;
      inm[0] = cm2; inm[1] = qm.x; inm[2] = qm.y; inm[3] = qm.z;
      ind[0] = cd2; ind[1] = qd.x; ind[2] = qd.y; ind[3] = qd.z;
      cx = qx.w; cm2 = qm.w; cd2 = qd.w;
    } else {
      inx[0] = cx;  inx[1] = qx.w; inx[2] = qx.z; inx[3] = qx.y;
      inm[0] = cm2; inm[1] = qm.w; inm[2] = qm.z; inm[3] = qm.y;
      ind[0] = cd2; ind[1] = qd.w; ind[2] = qd.z; ind[3] = qd.y;
      cx = qx.x; cm2 = qm.x; cd2 = qd.x;
    }

    f32x4 pacc;
#pragma unroll
    for (int u = 0; u < 4; ++u) {
      unsigned* rec = (u & 1) ? rec1 : rec0;     // compile-time parity
      const float ix = inx[u], im = inm[u], idv = ind[u];
      f32x4 acc;
#pragma unroll
      for (int r = 0; r < 4; ++r)
        acc[r] = fmaf(vx[r], ix, fmaf(vy[r], im, fmaf(vz[r], idv, bs[r])));
      const short8 bh = __builtin_bit_cast(short8, Bh);
      const short8 bl = __builtin_bit_cast(short8, Bl);
      // depth-3 chain (same order as R8); wave0/wave1 are independent chains
      acc = __builtin_amdgcn_mfma_f32_16x16x32_bf16(Al, bh, acc, 0, 0, 0);
      acc = __builtin_amdgcn_mfma_f32_16x16x32_bf16(Ah, bl, acc, 0, 0, 0);
      acc = __builtin_amdgcn_mfma_f32_16x16x32_bf16(Ah, bh, acc, 0, 0, 0);
#pragma unroll
      for (int r = 0; r < 4; ++r) acc[r] = fmaxf(acc[r], 0.f);

      // per-lane U partial over this wave's 4 rows (cross-q + cross-wave
      // reduction deferred)
      float p = uu[0] * acc[0];
      p = fmaf(uu[1], acc[1], p); p = fmaf(uu[2], acc[2], p);
      p = fmaf(uu[3], acc[3], p);
      pacc[u] = p;

      // repack own half: hi = truncate via v_perm; lo = exact residual + RNE
      const unsigned h0 = __float_as_uint(acc[0]), h1 = __float_as_uint(acc[1]);
      const unsigned h2 = __float_as_uint(acc[2]), h3 = __float_as_uint(acc[3]);
      const unsigned oh0 = pk_hi(h1, h0), oh1 = pk_hi(h3, h2);
      unsigned ru[4];
#pragma unroll
      for (int r = 0; r < 4; ++r)
        ru[r] = __float_as_uint(acc[r] -
                 __uint_as_float(__float_as_uint(acc[r]) & 0xffff0000u)) + 0x8000u;
      const unsigned ol0 = pk_hi(ru[1], ru[0]), ol1 = pk_hi(ru[3], ru[2]);

      // write own half into the full-B record (wave0 -> slots 0-1/4-5,
      // wave1 -> slots 2-3/6-7), barrier, read assembled fragments.
      *(u32x2*)(rec + 2 * wave)     = (u32x2){oh0, oh1};
      *(u32x2*)(rec + 4 + 2 * wave) = (u32x2){ol0, ol1};
      __syncthreads();
      Bh = *(const u32x4*)rec;
      Bl = *(const u32x4*)(rec + 4);
    }
    // batched cross-q reduction within each wave
#pragma unroll
    for (int u = 0; u < 4; ++u) pacc[u] += __shfl_xor(pacc[u], 16);
#pragma unroll
    for (int u = 0; u < 4; ++u) pacc[u] += __shfl_xor(pacc[u], 32);

    // cross-wave sum: wave1 drops its quad partial, wave0 adds + stores
    if (wave == 1 && q == 0) *(f32x4*)pbuf[n] = pacc;
    __syncthreads();
    if (wave == 0 && q == 0) {
      const f32x4 o = *(const f32x4*)pbuf[n];
      if (!dir) {
        f32x4 s = {pacc[0] + o[0], pacc[1] + o[1],
                   pacc[2] + o[2], pacc[3] + o[3]};
        *(f32x4*)(pout + t0) = s;
      } else {
        f32x4 rev = {pacc[3] + o[3], pacc[2] + o[2],
                     pacc[1] + o[1], pacc[0] + o[0]};
        *(f32x4*)(pout + (Tn - 4 - t0)) = rev;       // pre-reversed
      }
    }
    qx = nqx; qm = nqm; qd = nqd;
  }
}

// out[i] = relu(pf[i] + pb[i] + c0[c]); pf staged in d_out, pb pre-reversed.
__global__ __launch_bounds__(256)
void mrnn_combine(const float* __restrict__ pb, const float* __restrict__ c0,
                  float* __restrict__ out) {
  const int i4 = blockIdx.x * 256 + threadIdx.x;
  const int c = (i4 >> 6) & (Cn - 1);
  const float c0v = c0[c];
  float4 a = ((const float4*)out)[i4];
  const float4 bb = ((const float4*)pb)[i4];
  a.x = fmaxf(a.x + bb.x + c0v, 0.f);
  a.y = fmaxf(a.y + bb.y + c0v, 0.f);
  a.z = fmaxf(a.z + bb.z + c0v, 0.f);
  a.w = fmaxf(a.w + bb.w + c0v, 0.f);
  ((float4*)out)[i4] = a;
}

extern "C" void kernel_launch(void* const* d_in, const int* in_sizes, int n_in,
                              void* d_out, int out_size, void* d_ws, size_t ws_size,
                              hipStream_t stream) {
  const float* x  = (const float*)d_in[0];
  const float* m  = (const float*)d_in[1];
  const float* dd = (const float*)d_in[2];
  const float* Wf = (const float*)d_in[3];
  const float* Vf = (const float*)d_in[4];
  const float* cf = (const float*)d_in[5];
  const float* Wb = (const float*)d_in[6];
  const float* Vb = (const float*)d_in[7];
  const float* cb = (const float*)d_in[8];
  const float* U  = (const float*)d_in[9];
  const float* c0 = (const float*)d_in[10];
  float* out = (float*)d_out;
  float* pb  = (float*)d_ws;   // B*C*T floats = 8 MB scratch

  mrnn_scan<<<1024, 128, 0, stream>>>(x, m, dd, Wf, Vf, cf, Wb, Vb, cb, U, out, pb);
  mrnn_combine<<<(Bn * Cn * Tn) / (256 * 4), 256, 0, stream>>>(pb, c0, out);
}

// Round 12
// 154.367 us; speedup vs baseline: 1.1773x; 1.1773x over previous
//
#include <hip/hip_runtime.h>

// mRNN B=128, C=64, H=32, T=256 via MFMA 16x16x32 bf16, split-bf16 (hi+lo).
// R12 = R8 structure (1024 single-wave blocks, one wave per (dir,c,16-batch),
// state resident in VGPRs, layout-closed recurrence) with two local edits:
//  (1) two depth-2 MFMA chains instead of one depth-3 chain per tile:
//      side = Wlo@hh + vinit -> + Whi@hl ; main = Whi@hh + 0 ;
//      acc = relu(main + side). Same 6 MFMAs/step, one less dependent-MFMA
//      latency on the recurrence critical path (z4-C form is R4-tested).
//  (2) unroll 8 steps/iter: halves carry/loop bookkeeping, batches the
//      cross-q reduction into one 8-wide shuffle window per 8 steps.
//
// Hard constraints learned this session:
//  - DO NOT template/dual-inline on dir (R6/R7 fail validation; R8 passes).
//  - DO NOT duplicate lanes for occupancy (R9: shared issue port, 2x demand).
//  - DO NOT split a chain across waves (R11: barrier + LDS round-trip on the
//    critical path costs more than the halved busy time).
//
// Layout-closed recurrence (R3/R5/R8-verified): h kept as B-operand fragment;
// row perm rho(m)=8*(m>>2)+(m&3) (+4 tile1) makes lane (q,n)'s C/D output
// exactly its next-step B fragment. No LDS anywhere in the recurrence.
//
// Precision (R5/R8-verified, absmax 4096 < 15155 thr): W=Whi+Wlo, h=hhi+hlo,
// hi=truncate (exact residual), lo=RNE.
constexpr int Bn = 128, Cn = 64, Hn = 32, Tn = 256;

typedef __attribute__((ext_vector_type(8))) short short8;
typedef __attribute__((ext_vector_type(4))) float f32x4;
typedef __attribute__((ext_vector_type(4))) unsigned int u32x4;

// pack top16(y):top16(x) -> one u32 (low half = x's top16)
__device__ __forceinline__ unsigned pk_hi(unsigned y, unsigned x) {
  return __builtin_amdgcn_perm(y, x, 0x07060302u);
}

__device__ __forceinline__ void wsplit(float w, short& hi, short& lo) {
  unsigned u = __float_as_uint(w);
  float r = w - __uint_as_float(u & 0xffff0000u);   // exact residual
  unsigned ru = __float_as_uint(r) + 0x8000u;       // RNE-ish lo
  hi = (short)(u >> 16);
  lo = (short)(ru >> 16);
}

__global__ __launch_bounds__(64, 1)
void mrnn_scan(const float* __restrict__ x, const float* __restrict__ m,
               const float* __restrict__ d,
               const float* __restrict__ Wf, const float* __restrict__ Vf,
               const float* __restrict__ cf,
               const float* __restrict__ Wb, const float* __restrict__ Vb,
               const float* __restrict__ cb,
               const float* __restrict__ U,
               float* __restrict__ pf_out, float* __restrict__ pb_out) {
  const int bid = blockIdx.x;
  const int dir = bid >> 9;                 // 0 fwd, 1 bwd
  const int c   = (bid >> 3) & (Cn - 1);
  const int g   = bid & 7;                  // batch group of 16
  const int tid = threadIdx.x;              // 0..63, one wave
  const int q = tid >> 4;
  const int n = tid & 15;
  const int b = g * 16 + n;

  const float* W  = dir ? Wb : Wf;
  const float* V  = dir ? Vb : Vf;
  const float* cc = dir ? cb : cf;

  // ---- A fragments: A[m=lane&15][k=8q+j], row perm rho(m)=8*(m>>2)+(m&3)
  const int ra0 = 8 * (n >> 2) + (n & 3);
  const int ra1 = ra0 + 4;
  short8 A0h, A0l, A1h, A1l;
#pragma unroll
  for (int j = 0; j < 8; ++j) {
    short hi, lo;
    wsplit(W[(c * Hn + ra0) * Hn + 8 * q + j], hi, lo); A0h[j] = hi; A0l[j] = lo;
    wsplit(W[(c * Hn + ra1) * Hn + 8 * q + j], hi, lo); A1h[j] = hi; A1l[j] = lo;
  }

  // ---- per-lane D rows: tile0 -> 8q+r, tile1 -> 8q+4+r
  float v0x[4], v0y[4], v0z[4], bs0[4], uu0[4];
  float v1x[4], v1y[4], v1z[4], bs1[4], uu1[4];
#pragma unroll
  for (int r = 0; r < 4; ++r) {
    const int row0 = 8 * q + r, row1 = row0 + 4;
    const float* vp0 = V + (c * Hn + row0) * 3;
    v0x[r] = vp0[0]; v0y[r] = vp0[1]; v0z[r] = vp0[2];
    bs0[r] = cc[c * Hn + row0];
    uu0[r] = U[c * 2 * Hn + dir * Hn + row0];
    const float* vp1 = V + (c * Hn + row1) * 3;
    v1x[r] = vp1[0]; v1y[r] = vp1[1]; v1z[r] = vp1[2];
    bs1[r] = cc[c * Hn + row1];
    uu1[r] = U[c * 2 * Hn + dir * Hn + row1];
  }

  // ---- state (B fragments)
  u32x4 Bh = {0u, 0u, 0u, 0u};
  u32x4 Bl = {0u, 0u, 0u, 0u};
  const f32x4 z4 = {0.f, 0.f, 0.f, 0.f};

  const long base = ((long)b * Cn + c) * Tn;
  const float* px = x + base;
  const float* pm = m + base;
  const float* pd = d + base;
  float* pout = (dir ? pb_out : pf_out) + base;

  // input schedule (verified): fwd step t reads idx max(t-1,0);
  // bwd step s reads idx min(T-s, T-1). Carry + aligned 8-wide prefetch.
  float cx, cm2, cd2;
  f32x4 qx0, qx1, qm0, qm1, qd0, qd1;
  if (!dir) {
    cx = px[0]; cm2 = pm[0]; cd2 = pd[0];
    qx0 = *(const f32x4*)px;        qx1 = *(const f32x4*)(px + 4);
    qm0 = *(const f32x4*)pm;        qm1 = *(const f32x4*)(pm + 4);
    qd0 = *(const f32x4*)pd;        qd1 = *(const f32x4*)(pd + 4);
  } else {
    cx = px[Tn - 1]; cm2 = pm[Tn - 1]; cd2 = pd[Tn - 1];
    qx0 = *(const f32x4*)(px + Tn - 8); qx1 = *(const f32x4*)(px + Tn - 4);
    qm0 = *(const f32x4*)(pm + Tn - 8); qm1 = *(const f32x4*)(pm + Tn - 4);
    qd0 = *(const f32x4*)(pd + Tn - 8); qd1 = *(const f32x4*)(pd + Tn - 4);
  }

  for (int t0 = 0; t0 < Tn; t0 += 8) {
    int qn_ = dir ? (Tn - 16 - t0) : (t0 + 8);
    if (qn_ < 0) qn_ = 0;
    if (qn_ > Tn - 8) qn_ = Tn - 8;
    const f32x4 nx0 = *(const f32x4*)(px + qn_), nx1 = *(const f32x4*)(px + qn_ + 4);
    const f32x4 nm0 = *(const f32x4*)(pm + qn_), nm1 = *(const f32x4*)(pm + qn_ + 4);
    const f32x4 nd0 = *(const f32x4*)(pd + qn_), nd1 = *(const f32x4*)(pd + qn_ + 4);

    // v[0..7] = the 8 loaded values per stream
    float vxa[8] = {qx0.x, qx0.y, qx0.z, qx0.w, qx1.x, qx1.y, qx1.z, qx1.w};
    float vma[8] = {qm0.x, qm0.y, qm0.z, qm0.w, qm1.x, qm1.y, qm1.z, qm1.w};
    float vda[8] = {qd0.x, qd0.y, qd0.z, qd0.w, qd1.x, qd1.y, qd1.z, qd1.w};
    float inx[8], inm[8], ind[8];
    inx[0] = cx; inm[0] = cm2; ind[0] = cd2;
    if (!dir) {
#pragma unroll
      for (int k = 1; k < 8; ++k) {
        inx[k] = vxa[k - 1]; inm[k] = vma[k - 1]; ind[k] = vda[k - 1];
      }
      cx = vxa[7]; cm2 = vma[7]; cd2 = vda[7];
    } else {
#pragma unroll
      for (int k = 1; k < 8; ++k) {
        inx[k] = vxa[8 - k]; inm[k] = vma[8 - k]; ind[k] = vda[8 - k];
      }
      cx = vxa[0]; cm2 = vma[0]; cd2 = vda[0];
    }

    float pacc[8];
#pragma unroll
    for (int u = 0; u < 8; ++u) {
      const float ix = inx[u], im = inm[u], idv = ind[u];
      f32x4 vi0, vi1;
#pragma unroll
      for (int r = 0; r < 4; ++r) {
        vi0[r] = fmaf(v0x[r], ix, fmaf(v0y[r], im, fmaf(v0z[r], idv, bs0[r])));
        vi1[r] = fmaf(v1x[r], ix, fmaf(v1y[r], im, fmaf(v1z[r], idv, bs1[r])));
      }
      const short8 bh = __builtin_bit_cast(short8, Bh);
      const short8 bl = __builtin_bit_cast(short8, Bl);
      // two depth-2 chains per tile (R12 edit 1):
      //   side = Wlo@hh + vinit -> + Whi@hl   (small terms)
      //   main = Whi@hh + 0                    (big term, depth 1)
      f32x4 s0 = __builtin_amdgcn_mfma_f32_16x16x32_bf16(A0l, bh, vi0, 0, 0, 0);
      f32x4 s1 = __builtin_amdgcn_mfma_f32_16x16x32_bf16(A1l, bh, vi1, 0, 0, 0);
      f32x4 a0 = __builtin_amdgcn_mfma_f32_16x16x32_bf16(A0h, bh, z4, 0, 0, 0);
      f32x4 a1 = __builtin_amdgcn_mfma_f32_16x16x32_bf16(A1h, bh, z4, 0, 0, 0);
      s0 = __builtin_amdgcn_mfma_f32_16x16x32_bf16(A0h, bl, s0, 0, 0, 0);
      s1 = __builtin_amdgcn_mfma_f32_16x16x32_bf16(A1h, bl, s1, 0, 0, 0);
      f32x4 acc0, acc1;
#pragma unroll
      for (int r = 0; r < 4; ++r) {
        acc0[r] = fmaxf(a0[r] + s0[r], 0.f);
        acc1[r] = fmaxf(a1[r] + s1[r], 0.f);
      }
      // per-lane U partial (fp32); cross-q reduction deferred to block end
      float p = uu0[0] * acc0[0];
      p = fmaf(uu0[1], acc0[1], p); p = fmaf(uu0[2], acc0[2], p);
      p = fmaf(uu0[3], acc0[3], p);
      p = fmaf(uu1[0], acc1[0], p); p = fmaf(uu1[1], acc1[1], p);
      p = fmaf(uu1[2], acc1[2], p); p = fmaf(uu1[3], acc1[3], p);
      pacc[u] = p;
      // repack state: hi = truncate via v_perm; lo = exact residual + RNE
      const unsigned h00 = __float_as_uint(acc0[0]), h01 = __float_as_uint(acc0[1]);
      const unsigned h02 = __float_as_uint(acc0[2]), h03 = __float_as_uint(acc0[3]);
      const unsigned h10 = __float_as_uint(acc1[0]), h11 = __float_as_uint(acc1[1]);
      const unsigned h12 = __float_as_uint(acc1[2]), h13 = __float_as_uint(acc1[3]);
      Bh[0] = pk_hi(h01, h00); Bh[1] = pk_hi(h03, h02);
      Bh[2] = pk_hi(h11, h10); Bh[3] = pk_hi(h13, h12);
      unsigned ru[8];
#pragma unroll
      for (int r = 0; r < 4; ++r) {
        ru[r]     = __float_as_uint(acc0[r] - __uint_as_float(__float_as_uint(acc0[r]) & 0xffff0000u)) + 0x8000u;
        ru[4 + r] = __float_as_uint(acc1[r] - __uint_as_float(__float_as_uint(acc1[r]) & 0xffff0000u)) + 0x8000u;
      }
      Bl[0] = pk_hi(ru[1], ru[0]); Bl[1] = pk_hi(ru[3], ru[2]);
      Bl[2] = pk_hi(ru[5], ru[4]); Bl[3] = pk_hi(ru[7], ru[6]);
    }
    // batched cross-q reduction: 8 independent xor-16, then 8 xor-32
#pragma unroll
    for (int u = 0; u < 8; ++u) pacc[u] += __shfl_xor(pacc[u], 16);
#pragma unroll
    for (int u = 0; u < 8; ++u) pacc[u] += __shfl_xor(pacc[u], 32);

    if (q == 0) {
      if (!dir) {
        f32x4 o0 = {pacc[0], pacc[1], pacc[2], pacc[3]};
        f32x4 o1 = {pacc[4], pacc[5], pacc[6], pacc[7]};
        *(f32x4*)(pout + t0) = o0;
        *(f32x4*)(pout + t0 + 4) = o1;
      } else {
        // positions Tn-8-t0+j hold step t0+(7-j)  (pre-reversed)
        f32x4 o0 = {pacc[7], pacc[6], pacc[5], pacc[4]};
        f32x4 o1 = {pacc[3], pacc[2], pacc[1], pacc[0]};
        *(f32x4*)(pout + (Tn - 8 - t0)) = o0;
        *(f32x4*)(pout + (Tn - 4 - t0)) = o1;
      }
    }
    qx0 = nx0; qx1 = nx1; qm0 = nm0; qm1 = nm1; qd0 = nd0; qd1 = nd1;
  }
}

// out[i] = relu(pf[i] + pb[i] + c0[c]); pf staged in d_out, pb pre-reversed.
__global__ __launch_bounds__(256)
void mrnn_combine(const float* __restrict__ pb, const float* __restrict__ c0,
                  float* __restrict__ out) {
  const int i4 = blockIdx.x * 256 + threadIdx.x;
  const int c = (i4 >> 6) & (Cn - 1);
  const float c0v = c0[c];
  float4 a = ((const float4*)out)[i4];
  const float4 bb = ((const float4*)pb)[i4];
  a.x = fmaxf(a.x + bb.x + c0v, 0.f);
  a.y = fmaxf(a.y + bb.y + c0v, 0.f);
  a.z = fmaxf(a.z + bb.z + c0v, 0.f);
  a.w = fmaxf(a.w + bb.w + c0v, 0.f);
  ((float4*)out)[i4] = a;
}

extern "C" void kernel_launch(void* const* d_in, const int* in_sizes, int n_in,
                              void* d_out, int out_size, void* d_ws, size_t ws_size,
                              hipStream_t stream) {
  const float* x  = (const float*)d_in[0];
  const float* m  = (const float*)d_in[1];
  const float* dd = (const float*)d_in[2];
  const float* Wf = (const float*)d_in[3];
  const float* Vf = (const float*)d_in[4];
  const float* cf = (const float*)d_in[5];
  const float* Wb = (const float*)d_in[6];
  const float* Vb = (const float*)d_in[7];
  const float* cb = (const float*)d_in[8];
  const float* U  = (const float*)d_in[9];
  const float* c0 = (const float*)d_in[10];
  float* out = (float*)d_out;
  float* pb  = (float*)d_ws;   // B*C*T floats = 8 MB scratch

  mrnn_scan<<<1024, 64, 0, stream>>>(x, m, dd, Wf, Vf, cf, Wb, Vb, cb, U, out, pb);
  mrnn_combine<<<(Bn * Cn * Tn) / (256 * 4), 256, 0, stream>>>(pb, c0, out);
}